// Round 19
// baseline (56.618 us; speedup 1.0000x reference)
//
#include <hip/hip_runtime.h>
#include <hip/hip_bf16.h>

#define A_N 8
#define C_N 256
#define H_N 80
#define W_N 108
#define P_N (H_N * W_N)      // 8640
#define P4_N (P_N / 4)       // 2160 float4 columns per plane
#define O_N 7
#define MH 256
#define MW 256
#define OUT_HW 256
#define TPA 17               // 128-px4 tiles per agent (17*128 = 2176 >= 2160)
#define NCG 8                // channel groups (32 ch each)
#define GCH 32               // channels per group

__device__ __forceinline__ float sigmoidf_(float zv) {
    return 1.0f / (1.0f + __expf(-zv));
}

// ---------------------------------------------------------------------------
// Run-length conv: block = 2 waves covering 128 CONTIGUOUS px4 of one
// 32-channel group; both waves march the same channel list in lockstep so
// the block's instantaneous loads form 2KB contiguous runs (r18 diagnosis:
// conv saturates ~2.6 TB/s with 256KB/CU in flight -> throughput wall from
// 1KB-island access pattern, not latency). Rolling 16-deep named-register
// load pipeline (r17's proven MLP trick). No cross-wave reduce (wave owns
// its px4). cm-resize + wsum*cm fold done ONLY by cg==0 blocks (sum over
// cg partials is mathematically identical). Partials -> k_finalize.
// Grid 8*17*8 = 1088 blocks x 128 thr.
// ---------------------------------------------------------------------------
__launch_bounds__(128, 4)
__global__ void k_convp(const float* __restrict__ x, const float* __restrict__ masks,
                        const float* __restrict__ w, float* __restrict__ part)
{
    __shared__ float s_w[GCH * 8];     // this block's 32 channels x [8]
    __shared__ float s_cm[512];        // resized mask for tile's 512 px (cg0 only)
    __shared__ float s_wpart[112];     // wsum partials (cg0 only)
    __shared__ float s_wsum[O_N];

    const int tid  = threadIdx.x;      // 0..127; px4-in-tile = tid
    const int bi   = blockIdx.x;
    const int cg   = bi & 7;
    const int t2   = bi >> 3;
    const int tile = t2 % TPA;
    const int a    = t2 / TPA;

    // ---- stage this group's 32 channels of w -> LDS [c_local][8] ----
    #pragma unroll
    for (int r = 0; r < 2; ++r) {
        const int e = r * 128 + tid;           // 256 entries
        const int cl = e >> 3, o = e & 7;
        s_w[e] = (o < O_N) ? w[o * C_N + cg * GCH + cl] : 0.0f;
    }

    if (cg == 0) {
        // ---- wsum partials: 112 threads = 7 o x 16 segments of 16 ch ----
        if (tid < 112) {
            const int o = tid >> 4, seg = tid & 15;
            const float4* wr = reinterpret_cast<const float4*>(w + o * C_N + seg * 16);
            float s = 0.0f;
            #pragma unroll
            for (int q = 0; q < 4; ++q) { float4 v = wr[q]; s += v.x + v.y + v.z + v.w; }
            s_wpart[tid] = s;
        }
        // ---- antialias resize (jax.image.resize bilinear, antialias=True),
        //      fixed 7x5 window; 512 px over 128 threads (4 px each) ----
        #pragma unroll
        for (int q4 = 0; q4 < 4; ++q4) {
            const int pi = tid * 4 + q4;                 // px within tile (0..511)
            const int px = min(tile * 512 + pi, P_N - 1);
            const int oy = px / W_N, ox = px - oy * W_N;
            const float ksy = 256.0f / 80.0f;
            const float ksx = 256.0f / 108.0f;
            const float rky = 0.3125f;                   // 80/256 exact
            const float rkx = 0.421875f;                 // 108/256 exact
            const float sfy = ((float)oy + 0.5f) * ksy - 0.5f;
            const float sfx = ((float)ox + 0.5f) * ksx - 0.5f;
            const int iyS = (int)ceilf(sfy - ksy);
            const int ixS = (int)ceilf(sfx - ksx);
            float wxv[5];
            float wxs = 0.0f;
            #pragma unroll
            for (int q = 0; q < 5; ++q) {
                const int ix = ixS + q;
                float wv = fmaxf(0.0f, 1.0f - fabsf(sfx - (float)ix) * rkx);
                wv = (ix >= 0 && ix < MW) ? wv : 0.0f;
                wxv[q] = wv;
                wxs += wv;
            }
            const float* mp = masks + (size_t)a * (MH * MW);
            float acm = 0.0f, wys = 0.0f;
            #pragma unroll
            for (int r = 0; r < 7; ++r) {
                const int iy = iyS + r;
                float wy = fmaxf(0.0f, 1.0f - fabsf(sfy - (float)iy) * rky);
                wy = (iy >= 0 && iy < MH) ? wy : 0.0f;
                wys += wy;
                const float* row = mp + min(max(iy, 0), MH - 1) * MW;
                float rs = 0.0f;
                #pragma unroll
                for (int q = 0; q < 5; ++q)
                    rs = fmaf(wxv[q], row[min(max(ixS + q, 0), MW - 1)], rs);
                acm = fmaf(wy, rs, acm);
            }
            s_cm[pi] = acm / (wys * wxs);
        }
    }
    __syncthreads();
    if (cg == 0 && tid < O_N) {
        float s = 0.0f;
        #pragma unroll
        for (int g = 0; g < 16; ++g) s += s_wpart[tid * 16 + g];
        s_wsum[tid] = s;
    }
    __syncthreads();

    // ---- main loop: 32 channels, rolling 16-deep load pipeline ----
    const int px4  = tile * 128 + tid;
    const int px4c = min(px4, P4_N - 1);
    const float* xp = x + ((size_t)(a * C_N + cg * GCH)) * P_N + (size_t)px4c * 4;

    float4 acc[O_N];
    #pragma unroll
    for (int o = 0; o < O_N; ++o) acc[o] = make_float4(0.f, 0.f, 0.f, 0.f);

#define LD(k) const float4 v##k = *reinterpret_cast<const float4*>(xp + (size_t)(k) * P_N);
#define FMA(k)                                                                 \
    {                                                                          \
        const float4 v = v##k;                                                 \
        const float* wc = s_w + (k) * 8;              /* wave-uniform */       \
        const float4 wA = *reinterpret_cast<const float4*>(wc);                \
        const float4 wB = *reinterpret_cast<const float4*>(wc + 4);            \
        acc[0].x = fmaf(wA.x, v.x, acc[0].x); acc[0].y = fmaf(wA.x, v.y, acc[0].y); \
        acc[0].z = fmaf(wA.x, v.z, acc[0].z); acc[0].w = fmaf(wA.x, v.w, acc[0].w); \
        acc[1].x = fmaf(wA.y, v.x, acc[1].x); acc[1].y = fmaf(wA.y, v.y, acc[1].y); \
        acc[1].z = fmaf(wA.y, v.z, acc[1].z); acc[1].w = fmaf(wA.y, v.w, acc[1].w); \
        acc[2].x = fmaf(wA.z, v.x, acc[2].x); acc[2].y = fmaf(wA.z, v.y, acc[2].y); \
        acc[2].z = fmaf(wA.z, v.z, acc[2].z); acc[2].w = fmaf(wA.z, v.w, acc[2].w); \
        acc[3].x = fmaf(wA.w, v.x, acc[3].x); acc[3].y = fmaf(wA.w, v.y, acc[3].y); \
        acc[3].z = fmaf(wA.w, v.z, acc[3].z); acc[3].w = fmaf(wA.w, v.w, acc[3].w); \
        acc[4].x = fmaf(wB.x, v.x, acc[4].x); acc[4].y = fmaf(wB.x, v.y, acc[4].y); \
        acc[4].z = fmaf(wB.x, v.z, acc[4].z); acc[4].w = fmaf(wB.x, v.w, acc[4].w); \
        acc[5].x = fmaf(wB.y, v.x, acc[5].x); acc[5].y = fmaf(wB.y, v.y, acc[5].y); \
        acc[5].z = fmaf(wB.y, v.z, acc[5].z); acc[5].w = fmaf(wB.y, v.w, acc[5].w); \
        acc[6].x = fmaf(wB.z, v.x, acc[6].x); acc[6].y = fmaf(wB.z, v.y, acc[6].y); \
        acc[6].z = fmaf(wB.z, v.z, acc[6].z); acc[6].w = fmaf(wB.z, v.w, acc[6].w); \
    }
    LD(0)  LD(1)  LD(2)  LD(3)  LD(4)  LD(5)  LD(6)  LD(7)
    LD(8)  LD(9)  LD(10) LD(11) LD(12) LD(13) LD(14) LD(15)
    FMA(0)  LD(16)
    FMA(1)  LD(17)
    FMA(2)  LD(18)
    FMA(3)  LD(19)
    FMA(4)  LD(20)
    FMA(5)  LD(21)
    FMA(6)  LD(22)
    FMA(7)  LD(23)
    FMA(8)  LD(24)
    FMA(9)  LD(25)
    FMA(10) LD(26)
    FMA(11) LD(27)
    FMA(12) LD(28)
    FMA(13) LD(29)
    FMA(14) LD(30)
    FMA(15) LD(31)
    FMA(16) FMA(17) FMA(18) FMA(19) FMA(20) FMA(21) FMA(22) FMA(23)
    FMA(24) FMA(25) FMA(26) FMA(27) FMA(28) FMA(29) FMA(30) FMA(31)
#undef LD
#undef FMA

    // ---- cg0: add full wsum*cm (covers the reference's x+cm add) ----
    if (cg == 0) {
        const float4 cm4 = reinterpret_cast<const float4*>(s_cm)[tid];
        #pragma unroll
        for (int o = 0; o < O_N; ++o) {
            const float ws = s_wsum[o];
            acc[o].x = fmaf(ws, cm4.x, acc[o].x);
            acc[o].y = fmaf(ws, cm4.y, acc[o].y);
            acc[o].z = fmaf(ws, cm4.z, acc[o].z);
            acc[o].w = fmaf(ws, cm4.w, acc[o].w);
        }
    }

    // ---- store partials (wave owns px4; no reduce) ----
    if (px4 < P4_N) {
        #pragma unroll
        for (int o = 0; o < O_N; ++o)
            reinterpret_cast<float4*>(part)[((size_t)(cg * A_N + a) * O_N + o) * P4_N + px4] = acc[o];
    }
}

// ---------------------------------------------------------------------------
// Finalize: z = sum_cg part[cg]; ssolo = sigmoid(z + b).
// Thread = (a*7+o, px4) pair: 120960 items, 473 blocks x 256.
// ---------------------------------------------------------------------------
__launch_bounds__(256)
__global__ void k_finalize(const float* __restrict__ part, const float* __restrict__ b,
                           float* __restrict__ z, float* __restrict__ ssolo)
{
    const int id = blockIdx.x * 256 + threadIdx.x;
    if (id >= A_N * O_N * P4_N) return;
    const int px4 = id % P4_N;
    const int ao  = id / P4_N;           // a*7+o, matches z/ssolo plane order
    const int o   = ao % O_N;

    const float4* p4 = reinterpret_cast<const float4*>(part);
    float4 s = p4[(size_t)ao * P4_N + px4];
    #pragma unroll
    for (int g = 1; g < NCG; ++g) {
        const float4 t = p4[((size_t)(g * A_N * O_N) + ao) * P4_N + px4];
        s.x += t.x; s.y += t.y; s.z += t.z; s.w += t.w;
    }
    reinterpret_cast<float4*>(z)[(size_t)ao * P4_N + px4] = s;
    const float bo = b[o];
    float4 sv;
    sv.x = sigmoidf_(s.x + bo);
    sv.y = sigmoidf_(s.y + bo);
    sv.z = sigmoidf_(s.z + bo);
    sv.w = sigmoidf_(s.w + bo);
    reinterpret_cast<float4*>(ssolo)[(size_t)ao * P4_N + px4] = sv;
}

// ---------------------------------------------------------------------------
// Aggregation, j-split for occupancy: wave0 = j 0..3 (+bias), wave1 = j 4..7;
// LDS combine. Grid 1080 blocks x 128 thr = 2160 waves (~8.4/CU, 2x r18).
// z planes 1.9 MB L2-resident gathers.
// ---------------------------------------------------------------------------
__launch_bounds__(128)
__global__ void k_aggr(const float* __restrict__ z, const float* __restrict__ rel,
                       const int* __restrict__ adj, const float* __restrict__ b,
                       float* __restrict__ saggr)
{
    __shared__ float s_p[O_N][64];
    const int tid  = threadIdx.x;
    const int lane = tid & 63;
    const int jb   = (tid >> 6) * 4;      // 0 or 4
    const int i = blockIdx.x / 135;
    const int p = (blockIdx.x - i * 135) * 64 + lane;
    const int vy = p / W_N, ux = p - vy * W_N;
    const float fu = (float)ux, fv = (float)vy;

    float acc[O_N];
    #pragma unroll
    for (int o = 0; o < O_N; ++o) acc[o] = (jb == 0) ? b[o] : 0.0f;

    for (int j = jb; j < jb + 4; ++j) {
        if (adj[i * A_N + j] == 0) continue;
        const float* M = rel + (i * A_N + j) * 6;
        float sx = M[0] * fu + M[1] * fv + M[2];
        float sy = M[3] * fu + M[4] * fv + M[5];
        if (!(sx > -1.0f && sx < (float)W_N && sy > -1.0f && sy < (float)H_N)) continue;
        float x0f = floorf(sx), y0f = floorf(sy);
        float wx = sx - x0f, wy = sy - y0f;
        int x0 = (int)x0f, y0 = (int)y0f;
        int x1 = x0 + 1,  y1 = y0 + 1;
        float w00 = (1.0f - wy) * (1.0f - wx), w01 = (1.0f - wy) * wx;
        float w10 = wy * (1.0f - wx),          w11 = wy * wx;
        if (x0 < 0)    { w00 = 0.0f; w10 = 0.0f; x0 = 0; }
        if (x1 >= W_N) { w01 = 0.0f; w11 = 0.0f; x1 = W_N - 1; }
        if (y0 < 0)    { w00 = 0.0f; w01 = 0.0f; y0 = 0; }
        if (y1 >= H_N) { w10 = 0.0f; w11 = 0.0f; y1 = H_N - 1; }
        const int i00 = y0 * W_N + x0, i01 = y0 * W_N + x1;
        const int i10 = y1 * W_N + x0, i11 = y1 * W_N + x1;
        const float* zj = z + j * O_N * P_N;
        #pragma unroll
        for (int o = 0; o < O_N; ++o) {
            const float* zp = zj + o * P_N;
            acc[o] += w00 * zp[i00] + w01 * zp[i01] + w10 * zp[i10] + w11 * zp[i11];
        }
    }
    if (tid >= 64) {
        #pragma unroll
        for (int o = 0; o < O_N; ++o) s_p[o][lane] = acc[o];
    }
    __syncthreads();
    if (tid < 64) {
        const int ob = i * O_N * P_N + p;
        #pragma unroll
        for (int o = 0; o < O_N; ++o)
            saggr[ob + o * P_N] = sigmoidf_(acc[o] + s_p[o][lane]);
    }
}

// ---------------------------------------------------------------------------
// Upsample: align_corners=True bilinear 80x108 -> 256x256, f32 out.
// 4 px/thread -> float4 stores; 7168 blocks x 256 exact.
// Output layout: [solo(8,7,256,256), aggr(8,7,256,256)] flat f32.
// ---------------------------------------------------------------------------
__launch_bounds__(256)
__global__ void k_upsample(const float* __restrict__ ssolo, const float* __restrict__ saggr,
                           float* __restrict__ out)
{
    const int idx = blockIdx.x * 256 + threadIdx.x;   // quad index
    int k = idx;
    const int oxq = k & 63;   k >>= 6;
    const int oy  = k & 255;  k >>= 8;
    const int o   = k % O_N;  k /= O_N;
    const int a   = k & 7;    k >>= 3;
    const int t   = k;        // 0 = solo, 1 = aggr

    const float* src = (t == 0 ? ssolo : saggr) + (a * O_N + o) * P_N;
    float syf = (float)oy * (79.0f / 255.0f);
    int y0 = (int)syf; y0 = min(y0, H_N - 2);
    float wy = syf - (float)y0;
    const float* r0 = src + y0 * W_N;
    const float* r1 = r0 + W_N;

    float res[4];
    #pragma unroll
    for (int q = 0; q < 4; ++q) {
        int ox = oxq * 4 + q;
        float sxf = (float)ox * (107.0f / 255.0f);
        int x0 = (int)sxf; x0 = min(x0, W_N - 2);
        float wx = sxf - (float)x0;
        float c0 = r0[x0]     * (1.0f - wy) + r1[x0]     * wy;
        float c1 = r0[x0 + 1] * (1.0f - wy) + r1[x0 + 1] * wy;
        res[q] = c0 * (1.0f - wx) + c1 * wx;
    }
    *reinterpret_cast<float4*>(out + (size_t)idx * 4) =
        make_float4(res[0], res[1], res[2], res[3]);
}

// ---------------------------------------------------------------------------
extern "C" void kernel_launch(void* const* d_in, const int* in_sizes, int n_in,
                              void* d_out, int out_size, void* d_ws, size_t ws_size,
                              hipStream_t stream)
{
    (void)in_sizes; (void)n_in; (void)out_size; (void)ws_size;
    const float* x    = (const float*)d_in[0];
    const float* rel  = (const float*)d_in[1];
    const int*   adj  = (const int*)d_in[2];
    const float* cmsk = (const float*)d_in[3];
    const float* wcls = (const float*)d_in[4];
    const float* bcls = (const float*)d_in[5];
    float* out = (float*)d_out;   // reference output dtype is float32

    float* ws    = (float*)d_ws;
    float* part  = ws;                          // 8*8*7*8640 = 3,870,720 f32 (15.5 MB)
    float* z     = part  + NCG * A_N * O_N * P_N;
    float* ssolo = z     + A_N * O_N * P_N;
    float* saggr = ssolo + A_N * O_N * P_N;     // total ~21.3 MB (ws is ~276 MB)

    k_convp   <<<A_N * TPA * NCG, 128, 0, stream>>>(x, cmsk, wcls, part);
    k_finalize<<<(A_N * O_N * P4_N + 255) / 256, 256, 0, stream>>>(part, bcls, z, ssolo);
    k_aggr    <<<1080, 128, 0, stream>>>(z, rel, adj, bcls, saggr);
    k_upsample<<<7168, 256, 0, stream>>>(ssolo, saggr, out);
}

// Round 20
// 38.662 us; speedup vs baseline: 1.4644x; 1.4644x over previous
//
#include <hip/hip_runtime.h>
#include <hip/hip_bf16.h>

#define A_N 8
#define C_N 256
#define H_N 80
#define W_N 108
#define P_N (H_N * W_N)      // 8640
#define P4_N (P_N / 4)       // 2160 float4 columns per plane
#define O_N 7
#define MH 256
#define MW 256
#define OUT_HW 256
#define BPA 135              // 16-px4 tiles per agent (135*16 = 2160 exact)

// padded weight table: +4 floats per 16 channels -> the 4 simultaneous
// cs-subgroup broadcasts land on banks 0,4,8,12 (unpadded: 4-way conflict)
#define W16OFF(c) ((c) * 8 + ((c) >> 4) * 4)
#define W16SIZE   (C_N * 8 + (C_N / 16) * 4)   // 2112 floats

__device__ __forceinline__ float sigmoidf_(float zv) {
    return 1.0f / (1.0f + __expf(-zv));
}

// ---------------------------------------------------------------------------
// Fused resize + conv == r17 (best: conv ~27us) + XCD-LOCAL agent mapping.
// ONE structural change vs r17: a = bi & 7 (consecutive blockIdx round-robin
// XCDs -> all 135 blocks of agent a land on XCD a). Each XCD then streams
// only its agent's 8.85MB slab instead of all 70.8MB through its private L2
// (fabric traffic 566MB -> 71MB; the ~27us conv wall == 566MB / ~34.5TB/s
// L2-fill + HBM floor arithmetic).
// Grid 8*135 = 1080 blocks x 256 thr (~4 blocks/CU = 16 waves/CU).
// Block = 16 px4 (64 px) x 256 ch; lane = cs*16+p; per-lane 16 channels,
// ALL 16 loads issued upfront as named regs (16KB in flight/wave) under
// __launch_bounds__(256,2) (128-VGPR budget; r19 lesson: anything tighter
// silently serializes). cm folded into FMA input: acc += w*(x+cm).
// ---------------------------------------------------------------------------
__launch_bounds__(256, 2)
__global__ void k_conv(const float* __restrict__ x, const float* __restrict__ masks,
                       const float* __restrict__ w, const float* __restrict__ b,
                       float* __restrict__ z, float* __restrict__ ssolo)
{
    __shared__ float  s_w[W16SIZE];          // padded w table (8.25 KB)
    __shared__ float4 s_red[4][16][O_N];     // per-wave partials (7 KB)
    __shared__ float  s_cm[64];              // resized mask, 64 px

    const int tid  = threadIdx.x;
    const int lane = tid & 63;
    const int wid  = tid >> 6;
    const int a    = blockIdx.x & 7;         // XCD-local agent (r20 change)
    const int tile = blockIdx.x >> 3;        // 0..134

    // ---- stage w -> LDS, thread = channel (pads never read) ----
    {
        const int c = tid;
        #pragma unroll
        for (int o = 0; o < 8; ++o)
            s_w[W16OFF(c) + o] = (o < O_N) ? w[o * C_N + c] : 0.0f;
    }

    // ---- inline antialias resize (jax.image.resize bilinear, antialias),
    //      fixed 7x5 window, threads 0..63 (one per px of this tile) ----
    if (tid < 64) {
        const int p  = tile * 64 + tid;          // within-agent pixel, < 8640
        const int oy = p / W_N, ox = p - oy * W_N;
        const float ksy = 256.0f / 80.0f;
        const float ksx = 256.0f / 108.0f;
        const float rky = 0.3125f;               // 80/256 exact
        const float rkx = 0.421875f;             // 108/256 exact
        const float sfy = ((float)oy + 0.5f) * ksy - 0.5f;
        const float sfx = ((float)ox + 0.5f) * ksx - 0.5f;
        const int iyS = (int)ceilf(sfy - ksy);
        const int ixS = (int)ceilf(sfx - ksx);

        float wxv[5];
        float wxs = 0.0f;
        #pragma unroll
        for (int q = 0; q < 5; ++q) {
            const int ix = ixS + q;
            float wv = fmaxf(0.0f, 1.0f - fabsf(sfx - (float)ix) * rkx);
            wv = (ix >= 0 && ix < MW) ? wv : 0.0f;
            wxv[q] = wv;
            wxs += wv;
        }
        const float* mp = masks + (size_t)a * (MH * MW);
        float acm = 0.0f, wys = 0.0f;
        #pragma unroll
        for (int r = 0; r < 7; ++r) {
            const int iy = iyS + r;
            float wy = fmaxf(0.0f, 1.0f - fabsf(sfy - (float)iy) * rky);
            wy = (iy >= 0 && iy < MH) ? wy : 0.0f;
            wys += wy;
            const float* row = mp + min(max(iy, 0), MH - 1) * MW;
            float rs = 0.0f;
            #pragma unroll
            for (int q = 0; q < 5; ++q)
                rs = fmaf(wxv[q], row[min(max(ixS + q, 0), MW - 1)], rs);
            acm = fmaf(wy, rs, acm);
        }
        s_cm[tid] = acm / (wys * wxs);
    }
    __syncthreads();

    // ---- conv: 16 channels per lane, ALL loads issued before any use ----
    const int p   = lane & 15;               // px4 within tile
    const int cs  = lane >> 4;               // channel subgroup (4)
    const int px4 = tile * 16 + p;           // < 2160 exact, no clamp
    const int cb  = wid * 64 + cs * 16;      // lane's first channel

    const float* xp = x + ((size_t)a * C_N + cb) * P_N + (size_t)px4 * 4;

#define LD(k) const float4 v##k = *reinterpret_cast<const float4*>(xp + (size_t)(k) * P_N);
    LD(0)  LD(1)  LD(2)  LD(3)  LD(4)  LD(5)  LD(6)  LD(7)
    LD(8)  LD(9)  LD(10) LD(11) LD(12) LD(13) LD(14) LD(15)
#undef LD

    const float4 cm4 = make_float4(s_cm[p * 4], s_cm[p * 4 + 1],
                                   s_cm[p * 4 + 2], s_cm[p * 4 + 3]);

    float4 acc[O_N];
    #pragma unroll
    for (int o = 0; o < O_N; ++o) acc[o] = make_float4(0.f, 0.f, 0.f, 0.f);

#define FMA(k)                                                                 \
    {                                                                          \
        float4 v = v##k;                                                       \
        v.x += cm4.x; v.y += cm4.y; v.z += cm4.z; v.w += cm4.w;                \
        const float4 wA = *reinterpret_cast<const float4*>(s_w + W16OFF(cb + (k)));     \
        const float4 wB = *reinterpret_cast<const float4*>(s_w + W16OFF(cb + (k)) + 4); \
        acc[0].x = fmaf(wA.x, v.x, acc[0].x); acc[0].y = fmaf(wA.x, v.y, acc[0].y);     \
        acc[0].z = fmaf(wA.x, v.z, acc[0].z); acc[0].w = fmaf(wA.x, v.w, acc[0].w);     \
        acc[1].x = fmaf(wA.y, v.x, acc[1].x); acc[1].y = fmaf(wA.y, v.y, acc[1].y);     \
        acc[1].z = fmaf(wA.y, v.z, acc[1].z); acc[1].w = fmaf(wA.y, v.w, acc[1].w);     \
        acc[2].x = fmaf(wA.z, v.x, acc[2].x); acc[2].y = fmaf(wA.z, v.y, acc[2].y);     \
        acc[2].z = fmaf(wA.z, v.z, acc[2].z); acc[2].w = fmaf(wA.z, v.w, acc[2].w);     \
        acc[3].x = fmaf(wA.w, v.x, acc[3].x); acc[3].y = fmaf(wA.w, v.y, acc[3].y);     \
        acc[3].z = fmaf(wA.w, v.z, acc[3].z); acc[3].w = fmaf(wA.w, v.w, acc[3].w);     \
        acc[4].x = fmaf(wB.x, v.x, acc[4].x); acc[4].y = fmaf(wB.x, v.y, acc[4].y);     \
        acc[4].z = fmaf(wB.x, v.z, acc[4].z); acc[4].w = fmaf(wB.x, v.w, acc[4].w);     \
        acc[5].x = fmaf(wB.y, v.x, acc[5].x); acc[5].y = fmaf(wB.y, v.y, acc[5].y);     \
        acc[5].z = fmaf(wB.y, v.z, acc[5].z); acc[5].w = fmaf(wB.y, v.w, acc[5].w);     \
        acc[6].x = fmaf(wB.z, v.x, acc[6].x); acc[6].y = fmaf(wB.z, v.y, acc[6].y);     \
        acc[6].z = fmaf(wB.z, v.z, acc[6].z); acc[6].w = fmaf(wB.z, v.w, acc[6].w);     \
    }
    FMA(0)  FMA(1)  FMA(2)  FMA(3)  FMA(4)  FMA(5)  FMA(6)  FMA(7)
    FMA(8)  FMA(9)  FMA(10) FMA(11) FMA(12) FMA(13) FMA(14) FMA(15)
#undef FMA

    // ---- intra-wave reduce over cs: xor-butterfly lanes 16, 32 ----
    #pragma unroll
    for (int o = 0; o < O_N; ++o) {
        acc[o].x += __shfl_xor(acc[o].x, 16); acc[o].y += __shfl_xor(acc[o].y, 16);
        acc[o].z += __shfl_xor(acc[o].z, 16); acc[o].w += __shfl_xor(acc[o].w, 16);
        acc[o].x += __shfl_xor(acc[o].x, 32); acc[o].y += __shfl_xor(acc[o].y, 32);
        acc[o].z += __shfl_xor(acc[o].z, 32); acc[o].w += __shfl_xor(acc[o].w, 32);
    }
    if (lane < 16) {
        #pragma unroll
        for (int o = 0; o < O_N; ++o) s_red[wid][lane][o] = acc[o];
    }
    __syncthreads();

    // ---- cross-wave reduce + epilogue: 112 = 16 px4 x 7 outputs ----
    if (tid < 16 * O_N) {
        const int p2 = tid & 15;
        const int o  = tid >> 4;
        const float4 s0 = s_red[0][p2][o];
        const float4 s1 = s_red[1][p2][o];
        const float4 s2 = s_red[2][p2][o];
        const float4 s3 = s_red[3][p2][o];
        float4 zv;
        zv.x = s0.x + s1.x + s2.x + s3.x;
        zv.y = s0.y + s1.y + s2.y + s3.y;
        zv.z = s0.z + s1.z + s2.z + s3.z;
        zv.w = s0.w + s1.w + s2.w + s3.w;
        const float bo = b[o];
        const size_t ob = (size_t)(a * O_N + o) * P4_N + tile * 16 + p2;
        reinterpret_cast<float4*>(z)[ob] = zv;
        float4 sv;
        sv.x = sigmoidf_(zv.x + bo);
        sv.y = sigmoidf_(zv.y + bo);
        sv.z = sigmoidf_(zv.z + bo);
        sv.w = sigmoidf_(zv.w + bo);
        reinterpret_cast<float4*>(ssolo)[ob] = sv;
    }
}

// ---------------------------------------------------------------------------
// Aggregation, j-split (r19, refcheck'd): wave0 = j 0..3 (+bias), wave1 =
// j 4..7; LDS combine. 1080 blocks x 128 thr (~8.4 waves/CU).
// z planes 1.9 MB L2/L3-resident gathers.
// ---------------------------------------------------------------------------
__launch_bounds__(128)
__global__ void k_aggr(const float* __restrict__ z, const float* __restrict__ rel,
                       const int* __restrict__ adj, const float* __restrict__ b,
                       float* __restrict__ saggr)
{
    __shared__ float s_p[O_N][64];
    const int tid  = threadIdx.x;
    const int lane = tid & 63;
    const int jb   = (tid >> 6) * 4;      // 0 or 4
    const int i = blockIdx.x / 135;
    const int p = (blockIdx.x - i * 135) * 64 + lane;
    const int vy = p / W_N, ux = p - vy * W_N;
    const float fu = (float)ux, fv = (float)vy;

    float acc[O_N];
    #pragma unroll
    for (int o = 0; o < O_N; ++o) acc[o] = (jb == 0) ? b[o] : 0.0f;

    for (int j = jb; j < jb + 4; ++j) {
        if (adj[i * A_N + j] == 0) continue;
        const float* M = rel + (i * A_N + j) * 6;
        float sx = M[0] * fu + M[1] * fv + M[2];
        float sy = M[3] * fu + M[4] * fv + M[5];
        if (!(sx > -1.0f && sx < (float)W_N && sy > -1.0f && sy < (float)H_N)) continue;
        float x0f = floorf(sx), y0f = floorf(sy);
        float wx = sx - x0f, wy = sy - y0f;
        int x0 = (int)x0f, y0 = (int)y0f;
        int x1 = x0 + 1,  y1 = y0 + 1;
        float w00 = (1.0f - wy) * (1.0f - wx), w01 = (1.0f - wy) * wx;
        float w10 = wy * (1.0f - wx),          w11 = wy * wx;
        if (x0 < 0)    { w00 = 0.0f; w10 = 0.0f; x0 = 0; }
        if (x1 >= W_N) { w01 = 0.0f; w11 = 0.0f; x1 = W_N - 1; }
        if (y0 < 0)    { w00 = 0.0f; w01 = 0.0f; y0 = 0; }
        if (y1 >= H_N) { w10 = 0.0f; w11 = 0.0f; y1 = H_N - 1; }
        const int i00 = y0 * W_N + x0, i01 = y0 * W_N + x1;
        const int i10 = y1 * W_N + x0, i11 = y1 * W_N + x1;
        const float* zj = z + j * O_N * P_N;
        #pragma unroll
        for (int o = 0; o < O_N; ++o) {
            const float* zp = zj + o * P_N;
            acc[o] += w00 * zp[i00] + w01 * zp[i01] + w10 * zp[i10] + w11 * zp[i11];
        }
    }
    if (tid >= 64) {
        #pragma unroll
        for (int o = 0; o < O_N; ++o) s_p[o][lane] = acc[o];
    }
    __syncthreads();
    if (tid < 64) {
        const int ob = i * O_N * P_N + p;
        #pragma unroll
        for (int o = 0; o < O_N; ++o)
            saggr[ob + o * P_N] = sigmoidf_(acc[o] + s_p[o][lane]);
    }
}

// ---------------------------------------------------------------------------
// Upsample: align_corners=True bilinear 80x108 -> 256x256, f32 out.
// 4 px/thread -> float4 stores; 7168 blocks x 256 exact.
// Output layout: [solo(8,7,256,256), aggr(8,7,256,256)] flat f32.
// ---------------------------------------------------------------------------
__launch_bounds__(256)
__global__ void k_upsample(const float* __restrict__ ssolo, const float* __restrict__ saggr,
                           float* __restrict__ out)
{
    const int idx = blockIdx.x * 256 + threadIdx.x;   // quad index
    int k = idx;
    const int oxq = k & 63;   k >>= 6;
    const int oy  = k & 255;  k >>= 8;
    const int o   = k % O_N;  k /= O_N;
    const int a   = k & 7;    k >>= 3;
    const int t   = k;        // 0 = solo, 1 = aggr

    const float* src = (t == 0 ? ssolo : saggr) + (a * O_N + o) * P_N;
    float syf = (float)oy * (79.0f / 255.0f);
    int y0 = (int)syf; y0 = min(y0, H_N - 2);
    float wy = syf - (float)y0;
    const float* r0 = src + y0 * W_N;
    const float* r1 = r0 + W_N;

    float res[4];
    #pragma unroll
    for (int q = 0; q < 4; ++q) {
        int ox = oxq * 4 + q;
        float sxf = (float)ox * (107.0f / 255.0f);
        int x0 = (int)sxf; x0 = min(x0, W_N - 2);
        float wx = sxf - (float)x0;
        float c0 = r0[x0]     * (1.0f - wy) + r1[x0]     * wy;
        float c1 = r0[x0 + 1] * (1.0f - wy) + r1[x0 + 1] * wy;
        res[q] = c0 * (1.0f - wx) + c1 * wx;
    }
    *reinterpret_cast<float4*>(out + (size_t)idx * 4) =
        make_float4(res[0], res[1], res[2], res[3]);
}

// ---------------------------------------------------------------------------
extern "C" void kernel_launch(void* const* d_in, const int* in_sizes, int n_in,
                              void* d_out, int out_size, void* d_ws, size_t ws_size,
                              hipStream_t stream)
{
    (void)in_sizes; (void)n_in; (void)out_size; (void)ws_size;
    const float* x    = (const float*)d_in[0];
    const float* rel  = (const float*)d_in[1];
    const int*   adj  = (const int*)d_in[2];
    const float* cmsk = (const float*)d_in[3];
    const float* wcls = (const float*)d_in[4];
    const float* bcls = (const float*)d_in[5];
    float* out = (float*)d_out;   // reference output dtype is float32

    float* ws    = (float*)d_ws;
    float* z     = ws;                          // 8*7*8640 = 483,840 f32
    float* ssolo = z     + A_N * O_N * P_N;
    float* saggr = ssolo + A_N * O_N * P_N;     // total ~5.8 MB

    k_conv    <<<A_N * BPA, 256, 0, stream>>>(x, cmsk, wcls, bcls, z, ssolo);
    k_aggr    <<<1080, 128, 0, stream>>>(z, rel, adj, bcls, saggr);
    k_upsample<<<7168, 256, 0, stream>>>(ssolo, saggr, out);
}